// Round 10
// baseline (2489.871 us; speedup 1.0000x reference)
//
#include <hip/hip_runtime.h>
#include <math.h>

#pragma clang fp contract(off)

#define NPIX 4096
#define BIGF 3.0e38f
#define SLOTS 16
#define QCHUNK 256

// ---------------- helpers ----------------

// value-only sorted insert (ascending) into top-5
__device__ __forceinline__ void ins5v(float v, float dl[5]) {
    if (v >= dl[4]) return;
    dl[4] = v;
#pragma unroll
    for (int u = 4; u > 0; --u)
        if (dl[u] < dl[u - 1]) { float t_ = dl[u]; dl[u] = dl[u - 1]; dl[u - 1] = t_; }
}

// np.logaddexp(x, 0) emulation: scalar libm path, fp64-rounded (≈correctly rounded fp32)
__device__ __forceinline__ float softplus_np(float x) {
    if (x > 0.f) {
        float ef = (float)exp((double)(-x));
        return x + (float)log1p((double)ef);
    } else if (x < 0.f) {
        float ef = (float)exp((double)x);
        return (float)log1p((double)ef);
    }
    return 0.69314718055994530942f;
}

// ---------------- raw GEMM: C[M][4096] = W[M][K] @ X[K][4096] (no bias/relu) ------
// per-(m,p) accumulation: fp32 FMA, k ascending — matches BLAS sgemm micro-kernel.

__global__ __launch_bounds__(256) void gemm_raw_kernel(
    const float* __restrict__ W, const float* __restrict__ X,
    float* __restrict__ C, int M, int K) {
    __shared__ float Ws[16][68];
    __shared__ float Xs[16][64];
    int t = threadIdx.x;
    int tx = t & 15, ty = t >> 4;
    int n0 = blockIdx.x * 64, m0 = blockIdx.y * 64;
    int wm = t >> 2, wk = (t & 3) * 4;
    int xk = t >> 4, xn = (t & 15) * 4;
    float acc[4][4] = {};
    for (int k0 = 0; k0 < K; k0 += 16) {
        float4 wv = *(const float4*)&W[(size_t)(m0 + wm) * K + k0 + wk];
        Ws[wk + 0][wm] = wv.x; Ws[wk + 1][wm] = wv.y;
        Ws[wk + 2][wm] = wv.z; Ws[wk + 3][wm] = wv.w;
        *(float4*)&Xs[xk][xn] = *(const float4*)&X[(size_t)(k0 + xk) * NPIX + n0 + xn];
        __syncthreads();
#pragma unroll
        for (int kk = 0; kk < 16; ++kk) {
            float4 a4 = *(float4*)&Ws[kk][ty * 4];
            float4 b4 = *(float4*)&Xs[kk][tx * 4];
            float ar[4] = {a4.x, a4.y, a4.z, a4.w};
            float br[4] = {b4.x, b4.y, b4.z, b4.w};
#pragma unroll
            for (int i = 0; i < 4; ++i)
#pragma unroll
                for (int j = 0; j < 4; ++j)
                    acc[i][j] = fmaf(ar[i], br[j], acc[i][j]);
        }
        __syncthreads();
    }
#pragma unroll
    for (int i = 0; i < 4; ++i) {
        int mrow = m0 + ty * 4 + i;
        float4 o;
        o.x = acc[i][0]; o.y = acc[i][1]; o.z = acc[i][2]; o.w = acc[i][3];
        *(float4*)&C[(size_t)mrow * NPIX + n0 + tx * 4] = o;
    }
}

// ---------------- BN+bias+relu in exact np op order ----------------
// t = h + b; t = (((t - m) * g) / sqrt(v + 1e-5)) + be; relu. div/sqrt fp64-rounded.

__global__ void bnrelu_kernel(float* __restrict__ H,
                              const float* __restrict__ b, const float* __restrict__ g,
                              const float* __restrict__ be, const float* __restrict__ m,
                              const float* __restrict__ v, int M) {
    int e = blockIdx.x * 256 + threadIdx.x;
    int mm = e >> 12;
    if (mm >= M) return;
    float t = H[e] + b[mm];
    t = t - m[mm];
    t = t * g[mm];
    float vv = v[mm] + 1e-5f;
    float s = (float)sqrt((double)vv);
    t = (float)((double)t / (double)s);
    t = t + be[mm];
    H[e] = fmaxf(t, 0.f);
}

// ---------------- qs/ks: sequential fp32 FMA dot + bias at end ----------------

__global__ void dotk_np_kernel(const float* __restrict__ H, const float* __restrict__ cw,
                               const float* __restrict__ cb, float* __restrict__ out, int C) {
    int p = blockIdx.x * 256 + threadIdx.x;
    float s = 0.f;
    for (int c = 0; c < C; ++c) s = fmaf(H[(size_t)c * NPIX + p], cw[c], s);
    out[p] = s + cb[0];
}

// ---------------- skn: numpy pairwise sum of fp32 squares ----------------
// 128-blocks: r[8] accumulators, combine ((r0+r1)+(r2+r3))+((r4+r5)+(r6+r7));
// blocks fold in a balanced binary tree (n=256: b0+b1; n=512: (b0+b1)+(b2+b3)).

__global__ void skn_np_kernel(const float* __restrict__ Y, float* __restrict__ skn, int C) {
    int p = blockIdx.x * 256 + threadIdx.x;
    int nb = C >> 7;
    float bs[4];
    for (int b = 0; b < nb; ++b) {
        int c0 = b << 7;
        float r[8];
#pragma unroll
        for (int k = 0; k < 8; ++k) {
            float y = Y[(size_t)(c0 + k) * NPIX + p];
            float q = y * y;
            r[k] = q;
        }
        for (int i = 8; i < 128; i += 8) {
#pragma unroll
            for (int k = 0; k < 8; ++k) {
                float y = Y[(size_t)(c0 + i + k) * NPIX + p];
                float q = y * y;
                r[k] = r[k] + q;
            }
        }
        bs[b] = ((r[0] + r[1]) + (r[2] + r[3])) + ((r[4] + r[5]) + (r[6] + r[7]));
    }
    float s = (nb == 2) ? (bs[0] + bs[1]) : ((bs[0] + bs[1]) + (bs[2] + bs[3]));
    skn[p] = s;
}

// ---------------- distance: np-exact fp32 pipeline ----------------
// dot: fp32 FMA sequential over c (sgemm order); d2 = (sq+sk) - 2*dot (np op order);
// d = sqrt32(max(d2,0)) via fp64-rounded sqrt.

__global__ __launch_bounds__(256) void dist_np_kernel(
    const float* __restrict__ XT, const float* __restrict__ YT,
    const float* __restrict__ sknq, const float* __restrict__ sknk,
    float* __restrict__ D, int C, int qbase) {
    __shared__ float Xs[16][64];
    __shared__ float Ys[16][128];
    int t = threadIdx.x;
    int tx = t & 15, ty = t >> 4;
    int q0 = qbase + blockIdx.y * 64;
    int k0 = blockIdx.x * 128;
    float acc[4][8] = {};
    for (int c0 = 0; c0 < C; c0 += 16) {
        *(float4*)&Xs[ty][tx * 4] =
            *(const float4*)&XT[(size_t)(c0 + ty) * NPIX + q0 + tx * 4];
        const float* ysrc = &YT[(size_t)(c0 + ty) * NPIX + k0 + tx * 8];
        *(float4*)&Ys[ty][tx * 8] = *(const float4*)&ysrc[0];
        *(float4*)&Ys[ty][tx * 8 + 4] = *(const float4*)&ysrc[4];
        __syncthreads();
#pragma unroll
        for (int kk = 0; kk < 16; ++kk) {
            float4 a4 = *(float4*)&Xs[kk][ty * 4];
            float4 b40 = *(float4*)&Ys[kk][tx * 8];
            float4 b41 = *(float4*)&Ys[kk][tx * 8 + 4];
            float ar[4] = {a4.x, a4.y, a4.z, a4.w};
            float br[8] = {b40.x, b40.y, b40.z, b40.w, b41.x, b41.y, b41.z, b41.w};
#pragma unroll
            for (int i = 0; i < 4; ++i)
#pragma unroll
                for (int j = 0; j < 8; ++j)
                    acc[i][j] = fmaf(ar[i], br[j], acc[i][j]);
        }
        __syncthreads();
    }
    float sk8[8];
    *(float4*)&sk8[0] = *(const float4*)&sknk[k0 + tx * 8];
    *(float4*)&sk8[4] = *(const float4*)&sknk[k0 + tx * 8 + 4];
#pragma unroll
    for (int i = 0; i < 4; ++i) {
        float sq = sknq[q0 + ty * 4 + i];
        int lq = q0 - qbase + ty * 4 + i;
        float tmp[8];
#pragma unroll
        for (int j = 0; j < 8; ++j) {
            float A = sq + sk8[j];
            float B = 2.0f * acc[i][j];
            float d2 = A - B;
            float dc = fmaxf(d2, 0.f);
            tmp[j] = (float)sqrt((double)dc);
        }
        *(float4*)&D[(size_t)lq * NPIX + k0 + tx * 8] = *(float4*)&tmp[0];
        *(float4*)&D[(size_t)lq * NPIX + k0 + tx * 8 + 4] = *(float4*)&tmp[4];
    }
}

// ---------------- selection + np-softmax weights ----------------
// kth = 5th smallest fp32 d; keep all d <= kth (ties); weights = np softmax
// with the numpy pairwise-tree denominator over the sparse 4096-row.

__global__ __launch_bounds__(256) void row_select_np_kernel(
    const float* __restrict__ D, const float* __restrict__ qs, const float* __restrict__ ks,
    int* __restrict__ isel, float* __restrict__ wsel, int qbase) {
    int p = qbase + blockIdx.x;
    const float* drow = D + (size_t)blockIdx.x * NPIX;
    int t = threadIdx.x;
    __shared__ float tops[256][5];
    __shared__ float l2[64][5];
    __shared__ float kth_sh;
    __shared__ int cnt;
    __shared__ int slotj[SLOTS];

    if (t == 0) cnt = 0;
    float dl[5] = {BIGF, BIGF, BIGF, BIGF, BIGF};
    for (int u = 0; u < 16; ++u) ins5v(drow[t + 256 * u], dl);
#pragma unroll
    for (int u = 0; u < 5; ++u) tops[t][u] = dl[u];
    __syncthreads();
    if (t < 64) {
        float md[5] = {BIGF, BIGF, BIGF, BIGF, BIGF};
        for (int i = 0; i < 4; ++i)
            for (int u = 0; u < 5; ++u) ins5v(tops[t * 4 + i][u], md);
#pragma unroll
        for (int u = 0; u < 5; ++u) l2[t][u] = md[u];
    }
    __syncthreads();
    if (t == 0) {
        float md[5] = {BIGF, BIGF, BIGF, BIGF, BIGF};
        for (int i = 0; i < 64; ++i)
            for (int u = 0; u < 5; ++u) ins5v(l2[i][u], md);
        kth_sh = md[4];
    }
    __syncthreads();
    float kth = kth_sh;
    for (int u = 0; u < 16; ++u) {
        int j = t + 256 * u;
        if (drow[j] <= kth) {
            int s = atomicAdd(&cnt, 1);
            if (s < SLOTS) slotj[s] = j;
        }
    }
    __syncthreads();
    if (t == 0) {
        int n = cnt < SLOTS ? cnt : SLOTS;
        // deterministic ascending-index order (matches np row scan order)
        for (int a = 1; a < n; ++a) {
            int key = slotj[a]; int b = a - 1;
            while (b >= 0 && slotj[b] > key) { slotj[b + 1] = slotj[b]; --b; }
            slotj[b + 1] = key;
        }
        float q = qs[p];
        float a[SLOTS], ev[SLOTS];
        float mx = -BIGF;
        for (int s = 0; s < n; ++s) {
            float x = q + ks[slotj[s]];
            a[s] = softplus_np(x);
            mx = fmaxf(mx, a[s]);
        }
        for (int s = 0; s < n; ++s)
            ev[s] = (float)exp((double)(a[s] - mx));
        // numpy pairwise-tree sum over sparse 4096-vector:
        // 32 blocks of 128; block: 8 residue accumulators + fixed combine;
        // blocks fold in a balanced binary tree. Zeros absorb exactly.
        float bs[32];
        for (int i = 0; i < 32; ++i) bs[i] = 0.f;
        int s2 = 0;
        while (s2 < n) {
            int b = slotj[s2] >> 7;
            float r[8] = {0.f, 0.f, 0.f, 0.f, 0.f, 0.f, 0.f, 0.f};
            while (s2 < n && (slotj[s2] >> 7) == b) {
                int res = slotj[s2] & 7;
                r[res] = r[res] + ev[s2];
                ++s2;
            }
            bs[b] = ((r[0] + r[1]) + (r[2] + r[3])) + ((r[4] + r[5]) + (r[6] + r[7]));
        }
        float t16[16], t8[8], t4[4], t2[2];
        for (int i = 0; i < 16; ++i) t16[i] = bs[2 * i] + bs[2 * i + 1];
        for (int i = 0; i < 8; ++i) t8[i] = t16[2 * i] + t16[2 * i + 1];
        for (int i = 0; i < 4; ++i) t4[i] = t8[2 * i] + t8[2 * i + 1];
        for (int i = 0; i < 2; ++i) t2[i] = t4[2 * i] + t4[2 * i + 1];
        float ssum = t2[0] + t2[1];
        for (int s = 0; s < SLOTS; ++s) {
            float w = (s < n) ? (float)((double)ev[s] / (double)ssum) : 0.f;
            wsel[s * NPIX + p] = w;
            isel[s * NPIX + p] = (s < n) ? slotj[s] : 0;
        }
    }
}

// ---------------- gather: att@vals row — ascending-j fp32 FMA ----------------

__global__ void gather_np_kernel(const float* __restrict__ V,
                                 const int* __restrict__ isel, const float* __restrict__ wsel,
                                 float* __restrict__ out, int CV) {
    int g = blockIdx.x * 256 + threadIdx.x;
    int p = g & (NPIX - 1);
    int c = g >> 12;
    if (c >= CV) return;
    const float* Vc = V + (size_t)c * NPIX;
    float s = 0.f;
#pragma unroll
    for (int tt = 0; tt < SLOTS; ++tt) {
        float w = wsel[tt * NPIX + p];
        int j = isel[tt * NPIX + p];
        s = fmaf(w, Vc[j], s);   // zero-weight slots: fma(0,v,s)=s exact
    }
    out[(size_t)c * NPIX + p] = s;
}

// ---------------- launch ----------------

extern "C" void kernel_launch(void* const* d_in, const int* in_sizes, int n_in,
                              void* d_out, int out_size, void* d_ws, size_t ws_size,
                              hipStream_t stream) {
    const float* ip = (const float*)d_in[0];   // inp_cont   [256][4096]
    const float* pp = (const float*)d_in[2];   // peers_cont [256][4096]
    const float* ps = (const float*)d_in[3];   // peers_style[512][4096]
    const float* w1c = (const float*)d_in[4];
    const float* b1c = (const float*)d_in[5];
    const float* g1c = (const float*)d_in[6];
    const float* be1c = (const float*)d_in[7];
    const float* m1c = (const float*)d_in[8];
    const float* v1c = (const float*)d_in[9];
    const float* w2c = (const float*)d_in[10];
    const float* b2c = (const float*)d_in[11];
    const float* g2c = (const float*)d_in[12];
    const float* be2c = (const float*)d_in[13];
    const float* m2c = (const float*)d_in[14];
    const float* v2c = (const float*)d_in[15];
    const float* c1cw = (const float*)d_in[16];
    const float* c1cb = (const float*)d_in[17];
    const float* c2cw = (const float*)d_in[18];
    const float* c2cb = (const float*)d_in[19];
    const float* w1s = (const float*)d_in[20];
    const float* b1s = (const float*)d_in[21];
    const float* g1s = (const float*)d_in[22];
    const float* be1s = (const float*)d_in[23];
    const float* m1s = (const float*)d_in[24];
    const float* v1s = (const float*)d_in[25];
    const float* w2s = (const float*)d_in[26];
    const float* b2s = (const float*)d_in[27];
    const float* g2s = (const float*)d_in[28];
    const float* be2s = (const float*)d_in[29];
    const float* m2s = (const float*)d_in[30];
    const float* v2s = (const float*)d_in[31];
    const float* c1sw = (const float*)d_in[32];
    const float* c1sb = (const float*)d_in[33];
    const float* c2sw = (const float*)d_in[34];
    const float* c2sb = (const float*)d_in[35];

    float* out_cont = (float*)d_out;                 // [256][4096]
    float* out_sty = (float*)d_out + 256 * NPIX;     // [512][4096]

    // workspace layout (floats); total 2,768,896 fl = 11.1 MB
    float* ws = (float*)d_ws;
    float* QS   = ws + 0;
    float* KS   = ws + 4096;
    float* SKNQ = ws + 8192;
    float* SKNK = ws + 12288;
    float* WSEL = ws + 16384;           // 16*4096
    int*   ISEL = (int*)(ws + 81920);   // 16*4096
    float* H1   = ws + 147456;          // 256*4096
    float* H2   = ws + 1196032;         // 128*4096
    float* D    = ws + 1720320;         // 256*4096

    // ---- stage 1: content distance, gather style ----
    gemm_raw_kernel<<<dim3(64, 2), 256, 0, stream>>>(w1c, ip, H1, 128, 256);
    bnrelu_kernel<<<(128 * NPIX) / 256, 256, 0, stream>>>(H1, b1c, g1c, be1c, m1c, v1c, 128);
    gemm_raw_kernel<<<dim3(64, 1), 256, 0, stream>>>(w2c, H1, H2, 64, 128);
    bnrelu_kernel<<<(64 * NPIX) / 256, 256, 0, stream>>>(H2, b2c, g2c, be2c, m2c, v2c, 64);
    dotk_np_kernel<<<16, 256, 0, stream>>>(H2, c1cw, c1cb, QS, 64);
    gemm_raw_kernel<<<dim3(64, 2), 256, 0, stream>>>(w1c, pp, H1, 128, 256);
    bnrelu_kernel<<<(128 * NPIX) / 256, 256, 0, stream>>>(H1, b1c, g1c, be1c, m1c, v1c, 128);
    gemm_raw_kernel<<<dim3(64, 1), 256, 0, stream>>>(w2c, H1, H2, 64, 128);
    bnrelu_kernel<<<(64 * NPIX) / 256, 256, 0, stream>>>(H2, b2c, g2c, be2c, m2c, v2c, 64);
    dotk_np_kernel<<<16, 256, 0, stream>>>(H2, c2cw, c2cb, KS, 64);
    skn_np_kernel<<<16, 256, 0, stream>>>(ip, SKNQ, 256);
    skn_np_kernel<<<16, 256, 0, stream>>>(pp, SKNK, 256);
    for (int ch = 0; ch < 16; ++ch) {
        dist_np_kernel<<<dim3(32, 4), 256, 0, stream>>>(ip, pp, SKNQ, SKNK, D, 256, ch * QCHUNK);
        row_select_np_kernel<<<QCHUNK, 256, 0, stream>>>(D, QS, KS, ISEL, WSEL, ch * QCHUNK);
    }
    gather_np_kernel<<<(512 * NPIX) / 256, 256, 0, stream>>>(ps, ISEL, WSEL, out_sty, 512);

    // ---- stage 2: style distance, gather content ----
    gemm_raw_kernel<<<dim3(64, 4), 256, 0, stream>>>(w1s, out_sty, H1, 256, 512);
    bnrelu_kernel<<<(256 * NPIX) / 256, 256, 0, stream>>>(H1, b1s, g1s, be1s, m1s, v1s, 256);
    gemm_raw_kernel<<<dim3(64, 2), 256, 0, stream>>>(w2s, H1, H2, 128, 256);
    bnrelu_kernel<<<(128 * NPIX) / 256, 256, 0, stream>>>(H2, b2s, g2s, be2s, m2s, v2s, 128);
    dotk_np_kernel<<<16, 256, 0, stream>>>(H2, c1sw, c1sb, QS, 128);
    gemm_raw_kernel<<<dim3(64, 4), 256, 0, stream>>>(w1s, ps, H1, 256, 512);
    bnrelu_kernel<<<(256 * NPIX) / 256, 256, 0, stream>>>(H1, b1s, g1s, be1s, m1s, v1s, 256);
    gemm_raw_kernel<<<dim3(64, 2), 256, 0, stream>>>(w2s, H1, H2, 128, 256);
    bnrelu_kernel<<<(128 * NPIX) / 256, 256, 0, stream>>>(H2, b2s, g2s, be2s, m2s, v2s, 128);
    dotk_np_kernel<<<16, 256, 0, stream>>>(H2, c2sw, c2sb, KS, 128);
    skn_np_kernel<<<16, 256, 0, stream>>>(out_sty, SKNQ, 512);
    skn_np_kernel<<<16, 256, 0, stream>>>(ps, SKNK, 512);
    for (int ch = 0; ch < 16; ++ch) {
        dist_np_kernel<<<dim3(32, 4), 256, 0, stream>>>(out_sty, ps, SKNQ, SKNK, D, 512, ch * QCHUNK);
        row_select_np_kernel<<<QCHUNK, 256, 0, stream>>>(D, QS, KS, ISEL, WSEL, ch * QCHUNK);
    }
    gather_np_kernel<<<(256 * NPIX) / 256, 256, 0, stream>>>(pp, ISEL, WSEL, out_cont, 256);
}

// Round 11
// 887.484 us; speedup vs baseline: 2.8055x; 2.8055x over previous
//
#include <hip/hip_runtime.h>
#include <math.h>

#pragma clang fp contract(off)

#define NPIX 4096
#define BIGF 3.0e38f
#define SLOTS 16

// ---------------- helpers ----------------

// value-only sorted insert (ascending) into top-5
__device__ __forceinline__ void ins5v(float v, float dl[5]) {
    if (v >= dl[4]) return;
    dl[4] = v;
#pragma unroll
    for (int u = 4; u > 0; --u)
        if (dl[u] < dl[u - 1]) { float t_ = dl[u]; dl[u] = dl[u - 1]; dl[u - 1] = t_; }
}

// np.logaddexp(x, 0) emulation: scalar libm path, fp64-rounded (≈correctly rounded fp32)
__device__ __forceinline__ float softplus_np(float x) {
    if (x > 0.f) {
        float ef = (float)exp((double)(-x));
        return x + (float)log1p((double)ef);
    } else if (x < 0.f) {
        float ef = (float)exp((double)x);
        return (float)log1p((double)ef);
    }
    return 0.69314718055994530942f;
}

// ---------------- fused GEMM + BN + relu ----------------
// H[M][4096] = bn_relu(W[M][K] @ X[K][4096] + b)
// per-(m,p): fp32 FMA, k ascending (BLAS sgemm micro-kernel order), then the
// exact np op sequence: t=h+b; t-=m; t*=g; t/=sqrt64(v+eps); t+=be; relu.

__global__ __launch_bounds__(256) void gemm_bn_relu_kernel(
    const float* __restrict__ W, const float* __restrict__ X,
    const float* __restrict__ b, const float* __restrict__ g,
    const float* __restrict__ be, const float* __restrict__ m,
    const float* __restrict__ v,
    float* __restrict__ H, int M, int K) {
    __shared__ float Ws[16][68];
    __shared__ float Xs[16][68];
    int t = threadIdx.x;
    int tx = t & 15, ty = t >> 4;
    int n0 = blockIdx.x * 64, m0 = blockIdx.y * 64;
    int wm = t >> 2, wk = (t & 3) * 4;
    int xk = t >> 4, xn = (t & 15) * 4;
    float acc[4][4] = {};
    for (int k0 = 0; k0 < K; k0 += 16) {
        float4 wv = *(const float4*)&W[(size_t)(m0 + wm) * K + k0 + wk];
        Ws[wk + 0][wm] = wv.x; Ws[wk + 1][wm] = wv.y;
        Ws[wk + 2][wm] = wv.z; Ws[wk + 3][wm] = wv.w;
        *(float4*)&Xs[xk][xn] = *(const float4*)&X[(size_t)(k0 + xk) * NPIX + n0 + xn];
        __syncthreads();
#pragma unroll
        for (int kk = 0; kk < 16; ++kk) {
            float4 a4 = *(float4*)&Ws[kk][ty * 4];
            float4 b4 = *(float4*)&Xs[kk][tx * 4];
            float ar[4] = {a4.x, a4.y, a4.z, a4.w};
            float br[4] = {b4.x, b4.y, b4.z, b4.w};
#pragma unroll
            for (int i = 0; i < 4; ++i)
#pragma unroll
                for (int j = 0; j < 4; ++j)
                    acc[i][j] = fmaf(ar[i], br[j], acc[i][j]);
        }
        __syncthreads();
    }
#pragma unroll
    for (int i = 0; i < 4; ++i) {
        int mrow = m0 + ty * 4 + i;
        float bb = b[mrow];
        float mm_ = m[mrow];
        float gg = g[mrow];
        float vv = v[mrow] + 1e-5f;
        float ss = (float)sqrt((double)vv);
        float bee = be[mrow];
        float o[4];
#pragma unroll
        for (int j = 0; j < 4; ++j) {
            float t0 = acc[i][j] + bb;
            t0 = t0 - mm_;
            t0 = t0 * gg;
            t0 = (float)((double)t0 / (double)ss);
            t0 = t0 + bee;
            o[j] = fmaxf(t0, 0.f);
        }
        *(float4*)&H[(size_t)mrow * NPIX + n0 + tx * 4] = *(float4*)&o[0];
    }
}

// ---------------- qs/ks: sequential fp32 FMA dot + bias at end ----------------

__global__ void dotk_np_kernel(const float* __restrict__ H, const float* __restrict__ cw,
                               const float* __restrict__ cb, float* __restrict__ out, int C) {
    int p = blockIdx.x * 256 + threadIdx.x;
    float s = 0.f;
    for (int c = 0; c < C; ++c) s = fmaf(H[(size_t)c * NPIX + p], cw[c], s);
    out[p] = s + cb[0];
}

// ---------------- skn: numpy pairwise sum of fp32 squares ----------------

__global__ void skn_np_kernel(const float* __restrict__ Y, float* __restrict__ skn, int C) {
    int p = blockIdx.x * 256 + threadIdx.x;
    int nb = C >> 7;
    float bs[4];
    for (int b = 0; b < nb; ++b) {
        int c0 = b << 7;
        float r[8];
#pragma unroll
        for (int k = 0; k < 8; ++k) {
            float y = Y[(size_t)(c0 + k) * NPIX + p];
            float q = y * y;
            r[k] = q;
        }
        for (int i = 8; i < 128; i += 8) {
#pragma unroll
            for (int k = 0; k < 8; ++k) {
                float y = Y[(size_t)(c0 + i + k) * NPIX + p];
                float q = y * y;
                r[k] = r[k] + q;
            }
        }
        bs[b] = ((r[0] + r[1]) + (r[2] + r[3])) + ((r[4] + r[5]) + (r[6] + r[7]));
    }
    float s = (nb == 2) ? (bs[0] + bs[1]) : ((bs[0] + bs[1]) + (bs[2] + bs[3]));
    skn[p] = s;
}

// ---------------- distance: np-exact fp32 pipeline (padded LDS) ----------------

__global__ __launch_bounds__(256) void dist_np_kernel(
    const float* __restrict__ XT, const float* __restrict__ YT,
    const float* __restrict__ sknq, const float* __restrict__ sknk,
    float* __restrict__ D, int C, int qbase) {
    __shared__ float Xs[16][68];
    __shared__ float Ys[16][132];
    int t = threadIdx.x;
    int tx = t & 15, ty = t >> 4;
    int q0 = qbase + blockIdx.y * 64;
    int k0 = blockIdx.x * 128;
    float acc[4][8] = {};
    for (int c0 = 0; c0 < C; c0 += 16) {
        *(float4*)&Xs[ty][tx * 4] =
            *(const float4*)&XT[(size_t)(c0 + ty) * NPIX + q0 + tx * 4];
        const float* ysrc = &YT[(size_t)(c0 + ty) * NPIX + k0 + tx * 8];
        *(float4*)&Ys[ty][tx * 8] = *(const float4*)&ysrc[0];
        *(float4*)&Ys[ty][tx * 8 + 4] = *(const float4*)&ysrc[4];
        __syncthreads();
#pragma unroll
        for (int kk = 0; kk < 16; ++kk) {
            float4 a4 = *(float4*)&Xs[kk][ty * 4];
            float4 b40 = *(float4*)&Ys[kk][tx * 8];
            float4 b41 = *(float4*)&Ys[kk][tx * 8 + 4];
            float ar[4] = {a4.x, a4.y, a4.z, a4.w};
            float br[8] = {b40.x, b40.y, b40.z, b40.w, b41.x, b41.y, b41.z, b41.w};
#pragma unroll
            for (int i = 0; i < 4; ++i)
#pragma unroll
                for (int j = 0; j < 8; ++j)
                    acc[i][j] = fmaf(ar[i], br[j], acc[i][j]);
        }
        __syncthreads();
    }
    float sk8[8];
    *(float4*)&sk8[0] = *(const float4*)&sknk[k0 + tx * 8];
    *(float4*)&sk8[4] = *(const float4*)&sknk[k0 + tx * 8 + 4];
#pragma unroll
    for (int i = 0; i < 4; ++i) {
        float sq = sknq[q0 + ty * 4 + i];
        int lq = q0 - qbase + ty * 4 + i;
        float tmp[8];
#pragma unroll
        for (int j = 0; j < 8; ++j) {
            float A = sq + sk8[j];
            float B = 2.0f * acc[i][j];
            float d2 = A - B;
            float dc = fmaxf(d2, 0.f);
            tmp[j] = (float)sqrt((double)dc);
        }
        *(float4*)&D[(size_t)lq * NPIX + k0 + tx * 8] = *(float4*)&tmp[0];
        *(float4*)&D[(size_t)lq * NPIX + k0 + tx * 8 + 4] = *(float4*)&tmp[4];
    }
}

// ---------------- selection + np-softmax weights ----------------

__global__ __launch_bounds__(256) void row_select_np_kernel(
    const float* __restrict__ D, const float* __restrict__ qs, const float* __restrict__ ks,
    int* __restrict__ isel, float* __restrict__ wsel, int qbase) {
    int p = qbase + blockIdx.x;
    const float* drow = D + (size_t)blockIdx.x * NPIX;
    int t = threadIdx.x;
    __shared__ float tops[256][5];
    __shared__ float l2[64][5];
    __shared__ float kth_sh;
    __shared__ int cnt;
    __shared__ int slotj[SLOTS];

    if (t == 0) cnt = 0;
    float dl[5] = {BIGF, BIGF, BIGF, BIGF, BIGF};
    for (int u = 0; u < 16; ++u) ins5v(drow[t + 256 * u], dl);
#pragma unroll
    for (int u = 0; u < 5; ++u) tops[t][u] = dl[u];
    __syncthreads();
    if (t < 64) {
        float md[5] = {BIGF, BIGF, BIGF, BIGF, BIGF};
        for (int i = 0; i < 4; ++i)
            for (int u = 0; u < 5; ++u) ins5v(tops[t * 4 + i][u], md);
#pragma unroll
        for (int u = 0; u < 5; ++u) l2[t][u] = md[u];
    }
    __syncthreads();
    if (t == 0) {
        float md[5] = {BIGF, BIGF, BIGF, BIGF, BIGF};
        for (int i = 0; i < 64; ++i)
            for (int u = 0; u < 5; ++u) ins5v(l2[i][u], md);
        kth_sh = md[4];
    }
    __syncthreads();
    float kth = kth_sh;
    for (int u = 0; u < 16; ++u) {
        int j = t + 256 * u;
        if (drow[j] <= kth) {
            int s = atomicAdd(&cnt, 1);
            if (s < SLOTS) slotj[s] = j;
        }
    }
    __syncthreads();
    if (t == 0) {
        int n = cnt < SLOTS ? cnt : SLOTS;
        for (int a = 1; a < n; ++a) {
            int key = slotj[a]; int b = a - 1;
            while (b >= 0 && slotj[b] > key) { slotj[b + 1] = slotj[b]; --b; }
            slotj[b + 1] = key;
        }
        float q = qs[p];
        float a[SLOTS], ev[SLOTS];
        float mx = -BIGF;
        for (int s = 0; s < n; ++s) {
            float x = q + ks[slotj[s]];
            a[s] = softplus_np(x);
            mx = fmaxf(mx, a[s]);
        }
        for (int s = 0; s < n; ++s)
            ev[s] = (float)exp((double)(a[s] - mx));
        // numpy pairwise-tree sum over the sparse 4096-row (zeros absorb exactly)
        float bs[32];
        for (int i = 0; i < 32; ++i) bs[i] = 0.f;
        int s2 = 0;
        while (s2 < n) {
            int b = slotj[s2] >> 7;
            float r[8] = {0.f, 0.f, 0.f, 0.f, 0.f, 0.f, 0.f, 0.f};
            while (s2 < n && (slotj[s2] >> 7) == b) {
                int res = slotj[s2] & 7;
                r[res] = r[res] + ev[s2];
                ++s2;
            }
            bs[b] = ((r[0] + r[1]) + (r[2] + r[3])) + ((r[4] + r[5]) + (r[6] + r[7]));
        }
        float t16[16], t8[8], t4[4], t2[2];
        for (int i = 0; i < 16; ++i) t16[i] = bs[2 * i] + bs[2 * i + 1];
        for (int i = 0; i < 8; ++i) t8[i] = t16[2 * i] + t16[2 * i + 1];
        for (int i = 0; i < 4; ++i) t4[i] = t8[2 * i] + t8[2 * i + 1];
        for (int i = 0; i < 2; ++i) t2[i] = t4[2 * i] + t4[2 * i + 1];
        float ssum = t2[0] + t2[1];
        for (int s = 0; s < SLOTS; ++s) {
            float w = (s < n) ? (float)((double)ev[s] / (double)ssum) : 0.f;
            wsel[s * NPIX + p] = w;
            isel[s * NPIX + p] = (s < n) ? slotj[s] : 0;
        }
    }
}

// ---------------- gather: att@vals row — ascending-j fp32 FMA ----------------

__global__ void gather_np_kernel(const float* __restrict__ V,
                                 const int* __restrict__ isel, const float* __restrict__ wsel,
                                 float* __restrict__ out, int CV) {
    int g = blockIdx.x * 256 + threadIdx.x;
    int p = g & (NPIX - 1);
    int c = g >> 12;
    if (c >= CV) return;
    const float* Vc = V + (size_t)c * NPIX;
    float s = 0.f;
#pragma unroll
    for (int tt = 0; tt < SLOTS; ++tt) {
        float w = wsel[tt * NPIX + p];
        int j = isel[tt * NPIX + p];
        s = fmaf(w, Vc[j], s);
    }
    out[(size_t)c * NPIX + p] = s;
}

// ---------------- launch ----------------

extern "C" void kernel_launch(void* const* d_in, const int* in_sizes, int n_in,
                              void* d_out, int out_size, void* d_ws, size_t ws_size,
                              hipStream_t stream) {
    const float* ip = (const float*)d_in[0];   // inp_cont   [256][4096]
    const float* pp = (const float*)d_in[2];   // peers_cont [256][4096]
    const float* ps = (const float*)d_in[3];   // peers_style[512][4096]
    const float* w1c = (const float*)d_in[4];
    const float* b1c = (const float*)d_in[5];
    const float* g1c = (const float*)d_in[6];
    const float* be1c = (const float*)d_in[7];
    const float* m1c = (const float*)d_in[8];
    const float* v1c = (const float*)d_in[9];
    const float* w2c = (const float*)d_in[10];
    const float* b2c = (const float*)d_in[11];
    const float* g2c = (const float*)d_in[12];
    const float* be2c = (const float*)d_in[13];
    const float* m2c = (const float*)d_in[14];
    const float* v2c = (const float*)d_in[15];
    const float* c1cw = (const float*)d_in[16];
    const float* c1cb = (const float*)d_in[17];
    const float* c2cw = (const float*)d_in[18];
    const float* c2cb = (const float*)d_in[19];
    const float* w1s = (const float*)d_in[20];
    const float* b1s = (const float*)d_in[21];
    const float* g1s = (const float*)d_in[22];
    const float* be1s = (const float*)d_in[23];
    const float* m1s = (const float*)d_in[24];
    const float* v1s = (const float*)d_in[25];
    const float* w2s = (const float*)d_in[26];
    const float* b2s = (const float*)d_in[27];
    const float* g2s = (const float*)d_in[28];
    const float* be2s = (const float*)d_in[29];
    const float* m2s = (const float*)d_in[30];
    const float* v2s = (const float*)d_in[31];
    const float* c1sw = (const float*)d_in[32];
    const float* c1sb = (const float*)d_in[33];
    const float* c2sw = (const float*)d_in[34];
    const float* c2sb = (const float*)d_in[35];

    float* out_cont = (float*)d_out;                 // [256][4096]
    float* out_sty = (float*)d_out + 256 * NPIX;     // [512][4096]

    // workspace layout (floats)
    float* ws = (float*)d_ws;
    float* QS   = ws + 0;
    float* KS   = ws + 4096;
    float* SKNQ = ws + 8192;
    float* SKNK = ws + 12288;
    float* WSEL = ws + 16384;           // 16*4096
    int*   ISEL = (int*)(ws + 81920);   // 16*4096
    float* H1   = ws + 147456;          // 256*4096
    float* H2   = ws + 1196032;         // 128*4096
    float* D    = ws + 1720320;         // chunk_rows*4096

    // largest D chunk that fits (chunking only changes buffering, not results)
    size_t base = 1720320;
    int chunk = 256;
    if (ws_size >= (base + (size_t)4096 * NPIX) * 4) chunk = 4096;
    else if (ws_size >= (base + (size_t)2048 * NPIX) * 4) chunk = 2048;
    else if (ws_size >= (base + (size_t)1024 * NPIX) * 4) chunk = 1024;
    else if (ws_size >= (base + (size_t)512 * NPIX) * 4) chunk = 512;
    int nch = NPIX / chunk;

    // ---- stage 1: content distance, gather style ----
    gemm_bn_relu_kernel<<<dim3(64, 2), 256, 0, stream>>>(w1c, ip, b1c, g1c, be1c, m1c, v1c, H1, 128, 256);
    gemm_bn_relu_kernel<<<dim3(64, 1), 256, 0, stream>>>(w2c, H1, b2c, g2c, be2c, m2c, v2c, H2, 64, 128);
    dotk_np_kernel<<<16, 256, 0, stream>>>(H2, c1cw, c1cb, QS, 64);
    gemm_bn_relu_kernel<<<dim3(64, 2), 256, 0, stream>>>(w1c, pp, b1c, g1c, be1c, m1c, v1c, H1, 128, 256);
    gemm_bn_relu_kernel<<<dim3(64, 1), 256, 0, stream>>>(w2c, H1, b2c, g2c, be2c, m2c, v2c, H2, 64, 128);
    dotk_np_kernel<<<16, 256, 0, stream>>>(H2, c2cw, c2cb, KS, 64);
    skn_np_kernel<<<16, 256, 0, stream>>>(ip, SKNQ, 256);
    skn_np_kernel<<<16, 256, 0, stream>>>(pp, SKNK, 256);
    for (int ch = 0; ch < nch; ++ch) {
        dist_np_kernel<<<dim3(32, chunk / 64), 256, 0, stream>>>(ip, pp, SKNQ, SKNK, D, 256, ch * chunk);
        row_select_np_kernel<<<chunk, 256, 0, stream>>>(D, QS, KS, ISEL, WSEL, ch * chunk);
    }
    gather_np_kernel<<<(512 * NPIX) / 256, 256, 0, stream>>>(ps, ISEL, WSEL, out_sty, 512);

    // ---- stage 2: style distance, gather content ----
    gemm_bn_relu_kernel<<<dim3(64, 4), 256, 0, stream>>>(w1s, out_sty, b1s, g1s, be1s, m1s, v1s, H1, 256, 512);
    gemm_bn_relu_kernel<<<dim3(64, 2), 256, 0, stream>>>(w2s, H1, b2s, g2s, be2s, m2s, v2s, H2, 128, 256);
    dotk_np_kernel<<<16, 256, 0, stream>>>(H2, c1sw, c1sb, QS, 128);
    gemm_bn_relu_kernel<<<dim3(64, 4), 256, 0, stream>>>(w1s, ps, b1s, g1s, be1s, m1s, v1s, H1, 256, 512);
    gemm_bn_relu_kernel<<<dim3(64, 2), 256, 0, stream>>>(w2s, H1, b2s, g2s, be2s, m2s, v2s, H2, 128, 256);
    dotk_np_kernel<<<16, 256, 0, stream>>>(H2, c2sw, c2sb, KS, 128);
    skn_np_kernel<<<16, 256, 0, stream>>>(out_sty, SKNQ, 512);
    skn_np_kernel<<<16, 256, 0, stream>>>(ps, SKNK, 512);
    for (int ch = 0; ch < nch; ++ch) {
        dist_np_kernel<<<dim3(32, chunk / 64), 256, 0, stream>>>(out_sty, ps, SKNQ, SKNK, D, 512, ch * chunk);
        row_select_np_kernel<<<chunk, 256, 0, stream>>>(D, QS, KS, ISEL, WSEL, ch * chunk);
    }
    gather_np_kernel<<<(256 * NPIX) / 256, 256, 0, stream>>>(pp, ISEL, WSEL, out_cont, 256);
}